// Round 11
// baseline (148.238 us; speedup 1.0000x reference)
//
#include <hip/hip_runtime.h>
#include <math.h>

#define NBATCH 32
#define S      49152
#define NF     24          // frames (2048 samples each)
#define NB     16          // biquads
#define NBLK   8           // blocks per batch -> all 256 CUs
#define CHUNK  8           // samples per thread
#define NCH    768         // threads per block
#define NWAVE  12          // waves per block
// 8 blocks per batch; block covers 768*8 = 6144 samples = 3 frames.

__device__ __forceinline__ float clampf(float x, float lo, float hi) {
    return fminf(fmaxf(x, lo), hi);
}

// 8 named scalar signal registers -- guaranteed SSA (no alloca; R1-R4 showed
// the allocator pins VGPR at 84 and spills float arrays regardless of hints).
#define FOREACH_S(OP) \
    OP(s00) OP(s01) OP(s02) OP(s03) OP(s04) OP(s05) OP(s06) OP(s07)

#define DECL_S(x) float x;

// Phase A step: state only.  s' = T s + b*x
#define STEPA(x) { \
    const float n1_ = fmaf(t00, ic1, fmaf(t01, ic2, b0 * (x))); \
    const float n2_ = fmaf(t10, ic1, fmaf(t11, ic2, b1 * (x))); \
    ic1 = n1_; ic2 = n2_; }

// Phase C step: output + state.  y = c0*ic1 + c1*ic2 + c2*x, in place.
#define STEPC(x) { \
    const float y_  = fmaf(c0, ic1, fmaf(c1, ic2, c2 * (x))); \
    const float n1_ = fmaf(t00, ic1, fmaf(t01, ic2, b0 * (x))); \
    const float n2_ = fmaf(t10, ic1, fmaf(t11, ic2, b1 * (x))); \
    (x) = y_; ic1 = n1_; ic2 = n2_; }

// R10 post-mortem: per-round cost scales with in-round work (not a fixed sync
// overhead) -> revert to 2x2 rounds and attack work x parallelism instead:
//  - NBLK=8, CHUNK=8: all 256 CUs active, per-thread recurrence halves
//  - LDS power table M^1..M^64 (M=T^8) per (filter,frame): KS scan step and
//    lane-prefix binexp lose all in-loop matrix squarings (precomputed once)
//  - parallel predecessor poll: lane k polls slot k, 3-step shfl fold ->
//    1 L2 latency instead of up to 7 serial round trips
// Cross-block protocol unchanged (R6-proven write-once slots, tag=f+1 never
// equals the 0xAAAAAAAA ws poison; producers never wait -> no deadlock).
__global__ __launch_bounds__(NCH, 3)
void biquad_chain_kernel(const float* __restrict__ audio,
                         const float* __restrict__ params,
                         float* __restrict__ out,
                         unsigned int* __restrict__ ws)
{
    // per (filter,frame), stride 40:
    // [0..3]=t00,t01,t10,t11 [4..7]=b0,b1,c0,c1 [8]=c2
    // [12+4i .. 15+4i] = M^(2^i) for i=0..6  (M = T^8; M^64 = wave aggregate)
    __shared__ float sc[NB][NF][40];
    __shared__ float sgain[2][NF];     // [0]=in gain, [1]=out gain
    __shared__ float saggC[NWAVE][2];  // wave aggregate constants
    __shared__ float sv[NWAVE][2];     // per-wave incoming state

    const int t      = threadIdx.x;
    // XCD co-location swizzle (R8): 256 blocks, XCD = blockIdx % 8.
    // xcd owns batches [4*xcd, 4*xcd+4); all 8 eighths of a batch are at
    // blockIdx ≡ xcd (mod 8) -> same XCD, L2-local handshake.
    const int xcd    = blockIdx.x & 7;
    const int slot_  = blockIdx.x >> 3;          // 32 slots per XCD
    const int bt     = xcd * 4 + (slot_ & 3);    // batch
    const int eighth = slot_ >> 2;               // which eighth of the signal
    const int lane   = t & 63;
    const int wave   = t >> 6;
    const int frame  = eighth * 3 + (wave >> 2); // 4 waves per 2048-frame

    // ---------------- coefficient + power-table init (threads 0..383) --------
    if (t < NB * NF) {
        const int f  = t / NF;
        const int fr = t % NF;
        const float* P = params + (size_t)bt * 50 * NF;
        const float fn = P[(3 * f + 0) * NF + fr];
        const float gn = P[(3 * f + 1) * NF + fr];
        const float qn = P[(3 * f + 2) * NF + fr];

        float Q = __expf(-0.69314718f + qn * 3.4657359f);
        Q = clampf(Q, 0.1f, 100.0f);

        float lo, hi;
        int type;                        // 0 hp, 1 lp, 2 peak, 3 lowshelf, 4 highshelf
        if      (f == 0)  { lo = 20.0f;   hi = 500.0f;   type = 0; }
        else if (f == 15) { lo = 5000.0f; hi = 20000.0f; type = 1; }
        else if (f == 1)  { lo = 50.0f;   hi = 16000.0f; type = 3; }
        else if (f == 14) { lo = 50.0f;   hi = 16000.0f; type = 4; }
        else              { lo = 100.0f;  hi = 15000.0f; type = 2; }

        const float fc = __expf(__logf(lo) + fn * (__logf(hi) - __logf(lo)));
        float g_ = __tanf((float)M_PI * fc / 96000.0f);   // angle <= 0.655 rad
        g_ = clampf(g_, 1e-6f, 100.0f);
        const float gdb = -24.0f + 48.0f * gn;

        float a1, a2, a3, m0, m1, m2;
        if (type == 0 || type == 1) {
            const float k = 1.0f / Q;
            a1 = 1.0f / (1.0f + g_ * (g_ + k)); a2 = g_ * a1; a3 = g_ * a2;
            if (type == 0) { m0 = 1.0f; m1 = -k;   m2 = -1.0f; }
            else           { m0 = 0.0f; m1 = 0.0f; m2 = 1.0f;  }
        } else if (type == 2) {
            const float A = __expf(gdb * (2.30258509f / 40.0f));
            const float k = (gdb >= 0.0f) ? 1.0f / (Q * A) : A / Q;
            a1 = 1.0f / (1.0f + g_ * (g_ + k)); a2 = g_ * a1; a3 = g_ * a2;
            m0 = 1.0f; m1 = k * (A * A - 1.0f); m2 = 0.0f;
        } else {
            const float A  = __expf(gdb * (2.30258509f / 40.0f));
            const float sA = sqrtf(A);
            const float k  = 1.0f / Q;
            float gs;
            if (type == 3) gs = (gdb >= 0.0f) ? g_ / sA : g_ * sA;
            else           gs = (gdb >= 0.0f) ? g_ * sA : g_ / sA;
            a1 = 1.0f / (1.0f + gs * (gs + k)); a2 = gs * a1; a3 = gs * a2;
            if (type == 3) { m0 = 1.0f;  m1 = k * (A - 1.0f);      m2 = A * A - 1.0f; }
            else           { m0 = A * A; m1 = k * (1.0f - A) * A;  m2 = 1.0f - A * A; }
        }

        const float q2  = a2 * a2 + a3;
        const float t00 = 2.0f * a1 - 1.0f;
        const float t01 = -2.0f * a2;
        const float t10 = 2.0f * a1 * a2;
        const float t11 = 1.0f - 2.0f * q2;

        sc[f][fr][0] = t00; sc[f][fr][1] = t01; sc[f][fr][2] = t10; sc[f][fr][3] = t11;
        sc[f][fr][4] = 2.0f * a2;                   // b0
        sc[f][fr][5] = 2.0f * q2;                   // b1
        sc[f][fr][6] = a1 * (m1 + m2 * a2);         // c0
        sc[f][fr][7] = m2 * (1.0f - q2) - m1 * a2;  // c1
        sc[f][fr][8] = m0 + m1 * a2 + m2 * q2;      // c2

        // power table: M = T^8 (3 squarings), then M^2..M^64 (6 more)
        float u00 = t00, u01 = t01, u10 = t10, u11 = t11;
        #pragma unroll
        for (int i = 0; i < 3; i++) {
            const float n00 = u00*u00 + u01*u10;
            const float n01 = u00*u01 + u01*u11;
            const float n10 = u10*u00 + u11*u10;
            const float n11 = u10*u01 + u11*u11;
            u00=n00; u01=n01; u10=n10; u11=n11;
        }
        sc[f][fr][12] = u00; sc[f][fr][13] = u01; sc[f][fr][14] = u10; sc[f][fr][15] = u11;
        #pragma unroll
        for (int j = 1; j <= 6; j++) {
            const float n00 = u00*u00 + u01*u10;
            const float n01 = u00*u01 + u01*u11;
            const float n10 = u10*u00 + u11*u10;
            const float n11 = u10*u01 + u11*u11;
            u00=n00; u01=n01; u10=n10; u11=n11;
            sc[f][fr][12+4*j] = u00; sc[f][fr][13+4*j] = u01;
            sc[f][fr][14+4*j] = u10; sc[f][fr][15+4*j] = u11;
        }
    }
    if (t >= 384 && t < 384 + 2 * NF) {
        const int idx = t - 384;
        const int which = idx / NF;
        const int fr    = idx % NF;
        const float* P = params + (size_t)bt * 50 * NF;
        const float p  = P[(48 + which) * NF + fr];
        const float db = -60.0f + 60.0f * p;
        sgain[which][fr] = __expf(db * (2.30258509f / 20.0f));
    }
    __syncthreads();

    // ---------------- load chunk (with input gain) ----------------
    FOREACH_S(DECL_S)
    {
        const float ing = sgain[0][frame];
        const float* base = audio + (size_t)bt * S
                          + (size_t)(eighth * NCH + t) * CHUNK;
        float4 q;
        q = *(const float4*)(base + 0); s00 = q.x*ing; s01 = q.y*ing; s02 = q.z*ing; s03 = q.w*ing;
        q = *(const float4*)(base + 4); s04 = q.x*ing; s05 = q.y*ing; s06 = q.z*ing; s07 = q.w*ing;
    }

    // ---------------- 16 cascaded stages ----------------
    #pragma unroll 1
    for (int f = 0; f < NB; f++) {
        const float4 q0 = *(const float4*)&sc[f][frame][0];  // t00 t01 t10 t11
        const float4 q1 = *(const float4*)&sc[f][frame][4];  // b0 b1 c0 c1
        const float t00 = q0.x, t01 = q0.y, t10 = q0.z, t11 = q0.w;
        const float b0  = q1.x, b1  = q1.y, c0  = q1.z, c1  = q1.w;
        const float c2  = sc[f][frame][8];

        // Phase A: zero-state run over own chunk -> affine constant
        float ic1 = 0.0f, ic2 = 0.0f;
        FOREACH_S(STEPA)

        // constants-only Kogge-Stone; M^d from precomputed table (no squaring)
        float Ac0 = ic1, Ac1 = ic2;
        #pragma unroll
        for (int i = 0; i < 6; i++) {
            const int d = 1 << i;
            const float4 mv = *(const float4*)&sc[f][frame][12 + 4*i];
            const float lc0 = __shfl_up(Ac0, d);
            const float lc1 = __shfl_up(Ac1, d);
            if (lane >= d) {
                Ac0 = fmaf(mv.x, lc0, fmaf(mv.y, lc1, Ac0));
                Ac1 = fmaf(mv.z, lc0, fmaf(mv.w, lc1, Ac1));
            }
        }

        if (lane == 63) {
            saggC[wave][0] = Ac0; saggC[wave][1] = Ac1;
        }
        __syncthreads();

        const unsigned int tag = (unsigned int)(f + 1);
        unsigned int* stagebase = ws + ((bt * NB + f) * NBLK) * 8;

        // wave0: second-level scan over 12 wave aggregates, publish block
        // aggregate, parallel-poll predecessors, distribute per-wave v.
        if (wave == 0) {
            float G00 = 1.0f, G01 = 0.0f, G10 = 0.0f, G11 = 1.0f, Gc0 = 0.0f, Gc1 = 0.0f;
            if (lane < NWAVE) {
                // wave aggregate matrix = M^64 = T^512 of that wave's frame
                const float4 m = *(const float4*)&sc[f][eighth * 3 + (lane >> 2)][36];
                G00 = m.x; G01 = m.y; G10 = m.z; G11 = m.w;
                Gc0 = saggC[lane][0]; Gc1 = saggC[lane][1];
            }
            #pragma unroll
            for (int d = 1; d < 16; d <<= 1) {
                const float l00 = __shfl_up(G00, d);
                const float l01 = __shfl_up(G01, d);
                const float l10 = __shfl_up(G10, d);
                const float l11 = __shfl_up(G11, d);
                const float lc0 = __shfl_up(Gc0, d);
                const float lc1 = __shfl_up(Gc1, d);
                if (lane >= d && lane < NWAVE) {
                    const float n00 = G00 * l00 + G01 * l10;
                    const float n01 = G00 * l01 + G01 * l11;
                    const float n10 = G10 * l00 + G11 * l10;
                    const float n11 = G10 * l01 + G11 * l11;
                    const float nc0 = G00 * lc0 + G01 * lc1 + Gc0;
                    const float nc1 = G10 * lc0 + G11 * lc1 + Gc1;
                    G00 = n00; G01 = n01; G10 = n10; G11 = n11;
                    Gc0 = nc0; Gc1 = nc1;
                }
            }

            // publish block aggregate (inclusive at lane 11) ASAP
            if (eighth < NBLK - 1 && lane == NWAVE - 1) {
                unsigned int* slot = stagebase + eighth * 8;
                float* dp = (float*)(slot + 1);
                __hip_atomic_store(&dp[0], G00, __ATOMIC_RELAXED, __HIP_MEMORY_SCOPE_AGENT);
                __hip_atomic_store(&dp[1], G01, __ATOMIC_RELAXED, __HIP_MEMORY_SCOPE_AGENT);
                __hip_atomic_store(&dp[2], G10, __ATOMIC_RELAXED, __HIP_MEMORY_SCOPE_AGENT);
                __hip_atomic_store(&dp[3], G11, __ATOMIC_RELAXED, __HIP_MEMORY_SCOPE_AGENT);
                __hip_atomic_store(&dp[4], Gc0, __ATOMIC_RELAXED, __HIP_MEMORY_SCOPE_AGENT);
                __hip_atomic_store(&dp[5], Gc1, __ATOMIC_RELAXED, __HIP_MEMORY_SCOPE_AGENT);
                __hip_atomic_store(slot, tag, __ATOMIC_RELEASE, __HIP_MEMORY_SCOPE_AGENT);
            }

            // parallel predecessor poll: lane k polls slot k (k < eighth),
            // then 3-step inclusive compose-scan folds them in order.
            float Fm00 = 1.0f, Fm01 = 0.0f, Fm10 = 0.0f, Fm11 = 1.0f;
            float Fc0 = 0.0f, Fc1 = 0.0f;
            if (lane < eighth) {
                unsigned int* slot = stagebase + lane * 8;
                while (__hip_atomic_load(slot, __ATOMIC_ACQUIRE, __HIP_MEMORY_SCOPE_AGENT) != tag) {
                    __builtin_amdgcn_s_sleep(1);
                }
                float* dp = (float*)(slot + 1);
                Fm00 = __hip_atomic_load(&dp[0], __ATOMIC_RELAXED, __HIP_MEMORY_SCOPE_AGENT);
                Fm01 = __hip_atomic_load(&dp[1], __ATOMIC_RELAXED, __HIP_MEMORY_SCOPE_AGENT);
                Fm10 = __hip_atomic_load(&dp[2], __ATOMIC_RELAXED, __HIP_MEMORY_SCOPE_AGENT);
                Fm11 = __hip_atomic_load(&dp[3], __ATOMIC_RELAXED, __HIP_MEMORY_SCOPE_AGENT);
                Fc0  = __hip_atomic_load(&dp[4], __ATOMIC_RELAXED, __HIP_MEMORY_SCOPE_AGENT);
                Fc1  = __hip_atomic_load(&dp[5], __ATOMIC_RELAXED, __HIP_MEMORY_SCOPE_AGENT);
            }
            #pragma unroll
            for (int d = 1; d < 8; d <<= 1) {
                const float l00 = __shfl_up(Fm00, d);
                const float l01 = __shfl_up(Fm01, d);
                const float l10 = __shfl_up(Fm10, d);
                const float l11 = __shfl_up(Fm11, d);
                const float lc0 = __shfl_up(Fc0, d);
                const float lc1 = __shfl_up(Fc1, d);
                if (lane >= d && lane < 8) {
                    const float n00 = Fm00 * l00 + Fm01 * l10;
                    const float n01 = Fm00 * l01 + Fm01 * l11;
                    const float n10 = Fm10 * l00 + Fm11 * l10;
                    const float n11 = Fm10 * l01 + Fm11 * l11;
                    const float nc0 = Fm00 * lc0 + Fm01 * lc1 + Fc0;
                    const float nc1 = Fm10 * lc0 + Fm11 * lc1 + Fc1;
                    Fm00 = n00; Fm01 = n01; Fm10 = n10; Fm11 = n11;
                    Fc0 = nc0; Fc1 = nc1;
                }
            }
            float S0x = 0.0f, S0y = 0.0f;
            if (eighth > 0) {
                S0x = __shfl(Fc0, eighth - 1);
                S0y = __shfl(Fc1, eighth - 1);
            }

            // exclusive wave prefix
            float P00 = __shfl_up(G00, 1);
            float P01 = __shfl_up(G01, 1);
            float P10 = __shfl_up(G10, 1);
            float P11 = __shfl_up(G11, 1);
            float Pc0 = __shfl_up(Gc0, 1);
            float Pc1 = __shfl_up(Gc1, 1);
            if (lane == 0) { P00 = 1.0f; P01 = 0.0f; P10 = 0.0f; P11 = 1.0f; Pc0 = 0.0f; Pc1 = 0.0f; }

            // per-wave incoming state v = P(S0); lanes 0..11 write to LDS
            if (lane < NWAVE) {
                sv[lane][0] = fmaf(P00, S0x, fmaf(P01, S0y, Pc0));
                sv[lane][1] = fmaf(P10, S0x, fmaf(P11, S0y, Pc1));
            }
        }
        __syncthreads();

        const float vx = sv[wave][0];
        const float vy = sv[wave][1];

        // lane-exclusive constants
        float ce0 = __shfl_up(Ac0, 1);
        float ce1 = __shfl_up(Ac1, 1);
        if (lane == 0) { ce0 = 0.0f; ce1 = 0.0f; }

        // w = M^lane * v via binary exponentiation with precomputed powers
        float w0 = vx, w1 = vy;
        #pragma unroll
        for (int b = 0; b < 6; b++) {
            if (lane & (1 << b)) {
                const float4 mv = *(const float4*)&sc[f][frame][12 + 4*b];
                const float n0 = fmaf(mv.x, w0, mv.y * w1);
                const float n1 = fmaf(mv.z, w0, mv.w * w1);
                w0 = n0; w1 = n1;
            }
        }
        ic1 = w0 + ce0;
        ic2 = w1 + ce1;

        // Phase C: true run from incoming state, write outputs in place
        FOREACH_S(STEPC)
    }

    // ---------------- store (with output gain) ----------------
    {
        const float og = sgain[1][frame];
        float* base = out + (size_t)bt * S + (size_t)(eighth * NCH + t) * CHUNK;
        float4 q;
        q.x = s00*og; q.y = s01*og; q.z = s02*og; q.w = s03*og; *(float4*)(base + 0) = q;
        q.x = s04*og; q.y = s05*og; q.z = s06*og; q.w = s07*og; *(float4*)(base + 4) = q;
    }
}

extern "C" void kernel_launch(void* const* d_in, const int* in_sizes, int n_in,
                              void* d_out, int out_size, void* d_ws, size_t ws_size,
                              hipStream_t stream)
{
    const float* audio  = (const float*)d_in[0];
    const float* params = (const float*)d_in[1];
    float* out = (float*)d_out;
    unsigned int* ws = (unsigned int*)d_ws;
    biquad_chain_kernel<<<NBLK * NBATCH, NCH, 0, stream>>>(audio, params, out, ws);
}